// Round 2
// baseline (1099.107 us; speedup 1.0000x reference)
//
#include <hip/hip_runtime.h>
#include <hip/hip_bf16.h>

// Problem constants
#define BATCH   65536
#define IN_DIM  512
#define NRN     256
#define OUT_DIM 64
#define LIN_DIM 320

typedef _Float16 f16x8 __attribute__((ext_vector_type(8)));
typedef unsigned short u16x8 __attribute__((ext_vector_type(8)));
typedef float f32x4 __attribute__((ext_vector_type(4)));

__device__ __forceinline__ unsigned short h2u(_Float16 h) {
    return __builtin_bit_cast(unsigned short, h);
}
__device__ __forceinline__ float fast_tanh(float x) {
    // tanh(x) = 1 - 2/(exp(2x)+1); exact saturation at +/-inf
    float e = __expf(2.0f * x);
    return 1.0f - 2.0f / (e + 1.0f);
}

// ---------------- prep: weight conversion into workspace ----------------
// ws layout (bytes):
//   wlin_h : u16 [320][512]  offset 0        (327680)
//   wlin_l : u16 [320][512]  offset 327680   (327680)
//   wnlm   : f32 [255][256]  offset 655360   (261120)
//   wout_h : u16 [64][256]   offset 916480   (32768)
//   wout_l : u16 [64][256]   offset 949248   (32768)   total 982016
__global__ void cascade_prep(const float* __restrict__ W_lin,
                             const float* __restrict__ W_nl,
                             const float* __restrict__ W_out,
                             unsigned short* __restrict__ wlin_h,
                             unsigned short* __restrict__ wlin_l,
                             float* __restrict__ wnlm,
                             unsigned short* __restrict__ wout_h,
                             unsigned short* __restrict__ wout_l) {
    int idx = blockIdx.x * blockDim.x + threadIdx.x;
    int stride = gridDim.x * blockDim.x;
    for (int i = idx; i < LIN_DIM * IN_DIM; i += stride) {
        int n = i >> 9, k = i & 511;
        float w = W_lin[k * LIN_DIM + n];          // transpose -> [n][k]
        _Float16 h = (_Float16)w;
        _Float16 l = (_Float16)(w - (float)h);
        wlin_h[i] = h2u(h);
        wlin_l[i] = h2u(l);
    }
    for (int i = idx; i < (NRN - 1) * NRN; i += stride) {
        int r = i >> 8, k = i & 255;
        wnlm[i] = (k <= r) ? W_nl[i] : 0.0f;
    }
    for (int i = idx; i < OUT_DIM * NRN; i += stride) {
        float w = W_out[i];
        _Float16 h = (_Float16)w;
        _Float16 l = (_Float16)(w - (float)h);
        wout_h[i] = h2u(h);
        wout_l[i] = h2u(l);
    }
}

// ---------------- main fused kernel ----------------
// One block = 16 batch rows, 256 threads (4 waves).
// LDS plan (52.5 KB):
//   xh  : fp16 [16][520]  off 0       (16640)   } aliased by
//   tha : f32  [16][260]  off 0       (16640)   } (tha written after xh dead)
//   xl  : fp16 [16][520]  off 16640   (16640)
//   linc: f32  [16][256]  off 33280   (16384)
//   lino: f32  [16][64]   off 49664   (4096)    total 53760
__global__ __launch_bounds__(256, 3) void cascade_main(
    const float* __restrict__ x,
    const unsigned short* __restrict__ wlin_h,
    const unsigned short* __restrict__ wlin_l,
    const float* __restrict__ wnlm,
    const unsigned short* __restrict__ wout_h,
    const unsigned short* __restrict__ wout_l,
    float* __restrict__ out) {

    __shared__ __align__(16) char smem[53760];
    _Float16* xh   = (_Float16*)(smem);
    _Float16* xl   = (_Float16*)(smem + 16640);
    float*    linc = (float*)(smem + 33280);
    float*    lino = (float*)(smem + 49664);
    float*    tha  = (float*)(smem);               // aliases xh

    const int tid  = threadIdx.x;
    const int wv   = tid >> 6;
    const int lane = tid & 63;
    const int l15  = lane & 15;
    const int kb   = lane >> 4;       // 0..3
    const int row0 = blockIdx.x * 16;

    // ===== load x tile, split to fp16 hi/lo in LDS (coalesced) =====
    #pragma unroll
    for (int it = 0; it < 8; ++it) {
        int flat = it * 1024 + tid * 4;            // 16*512 = 8192 f32 total
        int r = flat >> 9, c = flat & 511;
        float4 v = *reinterpret_cast<const float4*>(x + (size_t)(row0 + r) * IN_DIM + c);
        _Float16 h0 = (_Float16)v.x, h1 = (_Float16)v.y, h2 = (_Float16)v.z, h3 = (_Float16)v.w;
        ushort4 uh = { h2u(h0), h2u(h1), h2u(h2), h2u(h3) };
        ushort4 ul = { h2u((_Float16)(v.x - (float)h0)), h2u((_Float16)(v.y - (float)h1)),
                       h2u((_Float16)(v.z - (float)h2)), h2u((_Float16)(v.w - (float)h3)) };
        *reinterpret_cast<ushort4*>(xh + r * 520 + c) = uh;
        *reinterpret_cast<ushort4*>(xl + r * 520 + c) = ul;
    }
    __syncthreads();

    // ===== stage 1: lin = x @ W_lin, fp16-split MFMA =====
    // 20 n-tiles; wave wv owns tiles {wv, wv+4, wv+8, wv+12, wv+16}.
    // Tiles 0..15 (cascade inputs): 3 products. Tiles 16..19 (lin_o): 1 product.
    {
        f32x4 acc[5] = {};
        for (int half = 0; half < 2; ++half) {
            f16x8 ah[8], al[8];
            #pragma unroll
            for (int k8 = 0; k8 < 8; ++k8) {
                int ks = half * 8 + k8;
                ah[k8] = *reinterpret_cast<const f16x8*>(xh + l15 * 520 + kb * 8 + ks * 32);
                al[k8] = *reinterpret_cast<const f16x8*>(xl + l15 * 520 + kb * 8 + ks * 32);
            }
            #pragma unroll
            for (int ti = 0; ti < 5; ++ti) {
                int n = wv + ti * 4;
                const unsigned short* bhp = wlin_h + (size_t)(n * 16 + l15) * IN_DIM + kb * 8 + half * 256;
                const unsigned short* blp = wlin_l + (size_t)(n * 16 + l15) * IN_DIM + kb * 8 + half * 256;
                #pragma unroll
                for (int k8 = 0; k8 < 8; ++k8) {
                    f16x8 bh = __builtin_bit_cast(f16x8, *reinterpret_cast<const u16x8*>(bhp + k8 * 32));
                    acc[ti] = __builtin_amdgcn_mfma_f32_16x16x32_f16(ah[k8], bh, acc[ti], 0, 0, 0);
                    if (ti < 4) {   // full precision only for cascade inputs
                        f16x8 bl = __builtin_bit_cast(f16x8, *reinterpret_cast<const u16x8*>(blp + k8 * 32));
                        acc[ti] = __builtin_amdgcn_mfma_f32_16x16x32_f16(al[k8], bh, acc[ti], 0, 0, 0);
                        acc[ti] = __builtin_amdgcn_mfma_f32_16x16x32_f16(ah[k8], bl, acc[ti], 0, 0, 0);
                    }
                }
            }
        }
        // D layout: col = lane&15, row = (lane>>4)*4 + j
        #pragma unroll
        for (int ti = 0; ti < 4; ++ti) {
            int c = (wv + ti * 4) * 16 + l15;
            #pragma unroll
            for (int j = 0; j < 4; ++j) linc[(kb * 4 + j) * 256 + c] = acc[ti][j];
        }
        {
            int c = wv * 16 + l15;
            #pragma unroll
            for (int j = 0; j < 4; ++j) lino[(kb * 4 + j) * 64 + c] = acc[4][j];
        }
    }
    __syncthreads();   // all waves done reading xh/xl; linc complete

    // ===== stage 2: serial cascade, f32, 16 lanes per row, wave-local =====
    {
        const int r = wv * 4 + (lane >> 4);   // block-local batch row
        const int t = l15;
        float* thr = tha + r * 260;
        const float* linr = linc + r * 256;

        // zero tanh buffer (masked weights make garbage*0 = 0 safe; must not be NaN)
        #pragma unroll
        for (int i = 0; i < 16; ++i) thr[t + i * 16] = 0.0f;

        if (t == 0) thr[0] = fast_tanh(linr[0] + 1.0f);

        const int k0 = t * 8, k1 = (t + 16) * 8;
        for (int j = 1; j < NRN; ++j) {
            const float* wr = wnlm + (size_t)(j - 1) * NRN;
            float part = 0.0f;
            if (k0 < j) {
                float4 a0 = *reinterpret_cast<const float4*>(thr + k0);
                float4 a1 = *reinterpret_cast<const float4*>(thr + k0 + 4);
                float4 w0 = *reinterpret_cast<const float4*>(wr + k0);
                float4 w1 = *reinterpret_cast<const float4*>(wr + k0 + 4);
                part += a0.x * w0.x + a0.y * w0.y + a0.z * w0.z + a0.w * w0.w
                      + a1.x * w1.x + a1.y * w1.y + a1.z * w1.z + a1.w * w1.w;
            }
            if (k1 < j) {
                float4 a0 = *reinterpret_cast<const float4*>(thr + k1);
                float4 a1 = *reinterpret_cast<const float4*>(thr + k1 + 4);
                float4 w0 = *reinterpret_cast<const float4*>(wr + k1);
                float4 w1 = *reinterpret_cast<const float4*>(wr + k1 + 4);
                part += a0.x * w0.x + a0.y * w0.y + a0.z * w0.z + a0.w * w0.w
                      + a1.x * w1.x + a1.y * w1.y + a1.z * w1.z + a1.w * w1.w;
            }
            part += __shfl_xor(part, 1, 64);
            part += __shfl_xor(part, 2, 64);
            part += __shfl_xor(part, 4, 64);
            part += __shfl_xor(part, 8, 64);
            float v = part + linr[j - 1] + 1.0f;
            float th = fast_tanh(v);
            if (t == ((j >> 3) & 15)) thr[j] = th;
        }
    }
    __syncthreads();   // all rows' tanh ready for stage 3

    // ===== stage 3: out = tanh @ W_out^T + lin_o + 1, fp16-split MFMA =====
    {
        const int n = wv;   // one 16-col tile per wave
        const unsigned short* bhp = wout_h + (size_t)(n * 16 + l15) * NRN + kb * 8;
        const unsigned short* blp = wout_l + (size_t)(n * 16 + l15) * NRN + kb * 8;
        f32x4 acc = {};
        #pragma unroll
        for (int ks = 0; ks < 8; ++ks) {
            const float* ap = tha + l15 * 260 + kb * 8 + ks * 32;
            float4 a0 = *reinterpret_cast<const float4*>(ap);
            float4 a1 = *reinterpret_cast<const float4*>(ap + 4);
            f16x8 ah, al;
            float av[8] = { a0.x, a0.y, a0.z, a0.w, a1.x, a1.y, a1.z, a1.w };
            #pragma unroll
            for (int e = 0; e < 8; ++e) {
                _Float16 h = (_Float16)av[e];
                ah[e] = h;
                al[e] = (_Float16)(av[e] - (float)h);
            }
            f16x8 bh = __builtin_bit_cast(f16x8, *reinterpret_cast<const u16x8*>(bhp + ks * 32));
            f16x8 bl = __builtin_bit_cast(f16x8, *reinterpret_cast<const u16x8*>(blp + ks * 32));
            acc = __builtin_amdgcn_mfma_f32_16x16x32_f16(ah, bh, acc, 0, 0, 0);
            acc = __builtin_amdgcn_mfma_f32_16x16x32_f16(al, bh, acc, 0, 0, 0);
            acc = __builtin_amdgcn_mfma_f32_16x16x32_f16(ah, bl, acc, 0, 0, 0);
        }
        #pragma unroll
        for (int j = 0; j < 4; ++j) {
            int r = kb * 4 + j, c = n * 16 + l15;
            out[(size_t)(row0 + r) * OUT_DIM + c] = acc[j] + lino[r * 64 + c] + 1.0f;
        }
    }
}

extern "C" void kernel_launch(void* const* d_in, const int* in_sizes, int n_in,
                              void* d_out, int out_size, void* d_ws, size_t ws_size,
                              hipStream_t stream) {
    (void)in_sizes; (void)n_in; (void)out_size; (void)ws_size;
    const float* x     = (const float*)d_in[0];
    const float* W_lin = (const float*)d_in[1];
    const float* W_nl  = (const float*)d_in[2];
    const float* W_out = (const float*)d_in[3];
    float* out = (float*)d_out;

    char* ws = (char*)d_ws;
    unsigned short* wlin_h = (unsigned short*)(ws);
    unsigned short* wlin_l = (unsigned short*)(ws + 327680);
    float*          wnlm   = (float*)(ws + 655360);
    unsigned short* wout_h = (unsigned short*)(ws + 916480);
    unsigned short* wout_l = (unsigned short*)(ws + 949248);

    cascade_prep<<<256, 256, 0, stream>>>(W_lin, W_nl, W_out,
                                          wlin_h, wlin_l, wnlm, wout_h, wout_l);
    cascade_main<<<BATCH / 16, 256, 0, stream>>>(x, wlin_h, wlin_l, wnlm,
                                                 wout_h, wout_l, out);
}

// Round 3
// 548.558 us; speedup vs baseline: 2.0036x; 2.0036x over previous
//
#include <hip/hip_runtime.h>
#include <hip/hip_bf16.h>

#define NRN     256
#define OUT_DIM 64

typedef _Float16 f16x8 __attribute__((ext_vector_type(8)));
typedef unsigned short u16x8 __attribute__((ext_vector_type(8)));
typedef float f32x4 __attribute__((ext_vector_type(4)));
typedef unsigned int u32x4 __attribute__((ext_vector_type(4)));

static __device__ __forceinline__ unsigned short h2u(_Float16 h) {
    return __builtin_bit_cast(unsigned short, h);
}
static __device__ __forceinline__ float fast_tanh(float x) {
    float e = __expf(2.0f * x);
    return 1.0f - 2.0f / (e + 1.0f);
}

// ---------------- prep: weight conversion into workspace ----------------
// ws layout (bytes):
//   wlin_h : u16 [320][512]  @ 0        (327680)   W_lin^T fp16 hi
//   wlin_l : u16 [320][512]  @ 327680   (327680)   W_lin^T fp16 lo
//   wnlm   : f32 [255][256]  @ 655360   (261120)   masked W_nl f32
//   wnl_h  : u16 [255][256]  @ 916480   (130560)   masked W_nl fp16 hi
//   wnl_l  : u16 [255][256]  @ 1047040  (130560)   masked W_nl fp16 lo
//   wout_h : u16 [64][256]   @ 1177600  (32768)
//   wout_l : u16 [64][256]   @ 1210368  (32768)    total 1243136
__global__ void cascade_prep(const float* __restrict__ W_lin,
                             const float* __restrict__ W_nl,
                             const float* __restrict__ W_out,
                             unsigned short* __restrict__ wlin_h,
                             unsigned short* __restrict__ wlin_l,
                             float* __restrict__ wnlm,
                             unsigned short* __restrict__ wnl_h,
                             unsigned short* __restrict__ wnl_l,
                             unsigned short* __restrict__ wout_h,
                             unsigned short* __restrict__ wout_l) {
    int idx = blockIdx.x * blockDim.x + threadIdx.x;
    int stride = gridDim.x * blockDim.x;
    for (int i = idx; i < 320 * 512; i += stride) {
        int n = i >> 9, k = i & 511;
        float w = W_lin[k * 320 + n];
        _Float16 h = (_Float16)w;
        wlin_h[i] = h2u(h);
        wlin_l[i] = h2u((_Float16)(w - (float)h));
    }
    for (int i = idx; i < 255 * 256; i += stride) {
        int r = i >> 8, k = i & 255;
        float w = (k <= r) ? W_nl[i] : 0.0f;
        wnlm[i] = w;
        _Float16 h = (_Float16)w;
        wnl_h[i] = h2u(h);
        wnl_l[i] = h2u((_Float16)(w - (float)h));
    }
    for (int i = idx; i < 64 * 256; i += stride) {
        float w = W_out[i];
        _Float16 h = (_Float16)w;
        wout_h[i] = h2u(h);
        wout_l[i] = h2u((_Float16)(w - (float)h));
    }
}

// build fp16 h/l MFMA A-fragments (h in low 16, l in high 16) from packed LDS
static __device__ __forceinline__ void tha_frag(const unsigned int* tha, int rr, int kbase,
                                                f16x8* ah, f16x8* al) {
    int base = rr * 256 + kbase;
    int swz = (rr & 7) << 2;
    u32x4 a0 = *reinterpret_cast<const u32x4*>(&tha[base ^ swz]);
    u32x4 a1 = *reinterpret_cast<const u32x4*>(&tha[(base + 4) ^ swz]);
    u32x4 hx, lx;
    hx[0] = (a0[0] & 0xffffu) | (a0[1] << 16);
    hx[1] = (a0[2] & 0xffffu) | (a0[3] << 16);
    hx[2] = (a1[0] & 0xffffu) | (a1[1] << 16);
    hx[3] = (a1[2] & 0xffffu) | (a1[3] << 16);
    lx[0] = (a0[0] >> 16) | (a0[1] & 0xffff0000u);
    lx[1] = (a0[2] >> 16) | (a0[3] & 0xffff0000u);
    lx[2] = (a1[0] >> 16) | (a1[1] & 0xffff0000u);
    lx[3] = (a1[2] >> 16) | (a1[3] & 0xffff0000u);
    *ah = __builtin_bit_cast(f16x8, hx);
    *al = __builtin_bit_cast(f16x8, lx);
}

static __device__ __forceinline__ float dot16(const float th[16], const float* wr) {
    float4 w0 = *reinterpret_cast<const float4*>(wr);
    float4 w1 = *reinterpret_cast<const float4*>(wr + 4);
    float4 w2 = *reinterpret_cast<const float4*>(wr + 8);
    float4 w3 = *reinterpret_cast<const float4*>(wr + 12);
    float s0 = th[0] * w0.x + th[1] * w0.y + th[2] * w0.z + th[3] * w0.w;
    float s1 = th[4] * w1.x + th[5] * w1.y + th[6] * w1.z + th[7] * w1.w;
    float s2 = th[8] * w2.x + th[9] * w2.y + th[10] * w2.z + th[11] * w2.w;
    float s3 = th[12] * w3.x + th[13] * w3.y + th[14] * w3.z + th[15] * w3.w;
    return (s0 + s1) + (s2 + s3);
}

// ---------------- fused main kernel ----------------
// 1 wave (64 threads) per block, 32 batch rows per block.
// LDS: tha 32768 + vT_lin 4096 + vT_con 4096 = 40960 B  -> 4 blocks/CU exactly.
__global__ __launch_bounds__(64, 1) void cascade_fused(
    const float* __restrict__ x,
    const unsigned short* __restrict__ wlin_h,
    const unsigned short* __restrict__ wlin_l,
    const float* __restrict__ wnlm,
    const unsigned short* __restrict__ wnl_h,
    const unsigned short* __restrict__ wnl_l,
    const unsigned short* __restrict__ wout_h,
    const unsigned short* __restrict__ wout_l,
    float* __restrict__ out) {

    __shared__ unsigned int tha[32 * 256];   // packed f16 h|l tanh values, swizzled
    __shared__ float vT_lin[32 * 32];        // [window col][row] lin window
    __shared__ float vT_con[32 * 32];        // [window col][row] inter-block contrib

    const int l   = threadIdx.x;
    const int l15 = l & 15;
    const int g   = l >> 4;     // 0..3 (k-group in MFMA frags / row-subgroup in D)
    const int r_s = l & 31;     // serial-phase batch row (block-local)
    const int h_s = l >> 5;     // serial-phase half (k-chunk owner)
    const long row0 = (long)blockIdx.x * 32;

    // ===== phase 0: load x tile as fp16 h/l MFMA A-fragments (registers) =====
    f16x8 xfh[2][16], xfl[2][16];
    #pragma unroll
    for (int m = 0; m < 2; ++m) {
        const float* xp = x + (row0 + m * 16 + l15) * 512 + g * 8;
        #pragma unroll
        for (int ks = 0; ks < 16; ++ks) {
            float4 p0 = *reinterpret_cast<const float4*>(xp + ks * 32);
            float4 p1 = *reinterpret_cast<const float4*>(xp + ks * 32 + 4);
            float av[8] = {p0.x, p0.y, p0.z, p0.w, p1.x, p1.y, p1.z, p1.w};
            f16x8 fh, fl;
            #pragma unroll
            for (int e = 0; e < 8; ++e) {
                _Float16 hh = (_Float16)av[e];
                fh[e] = hh;
                fl[e] = (_Float16)(av[e] - (float)hh);
            }
            xfh[m][ks] = fh;
            xfl[m][ks] = fl;
        }
    }

    float th_half[16];
    #pragma unroll
    for (int i = 0; i < 16; ++i) th_half[i] = 0.0f;
    float lin_carry = 0.0f;

    // ===== neuron-block loop: 8 blocks of 32 neurons =====
    for (int b = 0; b < 8; ++b) {
        __syncthreads();   // prev serial's tha writes / vT reads complete

        // --- lin window GEMM: cols [32b, 32b+32), K=512, fp16-split 3 products ---
        f32x4 acc2[2][2];
        f32x4 accC[2][2];
        #pragma unroll
        for (int m = 0; m < 2; ++m)
            #pragma unroll
            for (int n2 = 0; n2 < 2; ++n2) {
                acc2[m][n2] = (f32x4){0.f, 0.f, 0.f, 0.f};
                accC[m][n2] = (f32x4){0.f, 0.f, 0.f, 0.f};
            }
        #pragma unroll
        for (int ks = 0; ks < 16; ++ks) {
            #pragma unroll
            for (int n2 = 0; n2 < 2; ++n2) {
                const size_t brow = (size_t)(b * 32 + n2 * 16 + l15) * 512 + ks * 32 + g * 8;
                f16x8 bh = __builtin_bit_cast(f16x8, *reinterpret_cast<const u16x8*>(wlin_h + brow));
                f16x8 bl = __builtin_bit_cast(f16x8, *reinterpret_cast<const u16x8*>(wlin_l + brow));
                #pragma unroll
                for (int m = 0; m < 2; ++m) {
                    acc2[m][n2] = __builtin_amdgcn_mfma_f32_16x16x32_f16(xfh[m][ks], bh, acc2[m][n2], 0, 0, 0);
                    acc2[m][n2] = __builtin_amdgcn_mfma_f32_16x16x32_f16(xfl[m][ks], bh, acc2[m][n2], 0, 0, 0);
                    acc2[m][n2] = __builtin_amdgcn_mfma_f32_16x16x32_f16(xfh[m][ks], bl, acc2[m][n2], 0, 0, 0);
                }
            }
        }

        // --- inter-block contribution GEMM: K = 32b from tanh history in LDS ---
        for (int kc = 0; kc < b; ++kc) {
            f16x8 ah[2], al[2];
            #pragma unroll
            for (int m = 0; m < 2; ++m)
                tha_frag(tha, m * 16 + l15, kc * 32 + g * 8, &ah[m], &al[m]);
            #pragma unroll
            for (int n2 = 0; n2 < 2; ++n2) {
                const size_t wrow = (size_t)(b * 32 + n2 * 16 + l15 - 1) * 256 + kc * 32 + g * 8;
                f16x8 bh = __builtin_bit_cast(f16x8, *reinterpret_cast<const u16x8*>(wnl_h + wrow));
                f16x8 bl = __builtin_bit_cast(f16x8, *reinterpret_cast<const u16x8*>(wnl_l + wrow));
                #pragma unroll
                for (int m = 0; m < 2; ++m) {
                    accC[m][n2] = __builtin_amdgcn_mfma_f32_16x16x32_f16(ah[m], bh, accC[m][n2], 0, 0, 0);
                    accC[m][n2] = __builtin_amdgcn_mfma_f32_16x16x32_f16(al[m], bh, accC[m][n2], 0, 0, 0);
                    accC[m][n2] = __builtin_amdgcn_mfma_f32_16x16x32_f16(ah[m], bl, accC[m][n2], 0, 0, 0);
                }
            }
        }

        // --- bounce D-frags -> [col][row] transposed windows in LDS ---
        #pragma unroll
        for (int m = 0; m < 2; ++m)
            #pragma unroll
            for (int n2 = 0; n2 < 2; ++n2)
                #pragma unroll
                for (int j = 0; j < 4; ++j) {
                    int c = n2 * 16 + l15;
                    int rr = m * 16 + g * 4 + j;
                    vT_lin[c * 32 + rr] = acc2[m][n2][j];
                    vT_con[c * 32 + rr] = accC[m][n2][j];
                }
        __syncthreads();
        if (b == 0) lin_carry = vT_lin[0 * 32 + r_s];

        // --- serial intra-block cascade: 32 steps, lane-pair = one batch row ---
        // u = 0  (j = 32b; for b=0 this is neuron 0: v = lin[0] + 1)
        {
            const int j = b * 32;
            const int jm1 = (b == 0) ? 0 : (j - 1);
            const float* wr = wnlm + (size_t)jm1 * 256 + b * 32 + h_s * 16;
            float pa = dot16(th_half, wr);
            pa += __shfl_xor(pa, 32, 64);
            float v = (b == 0 ? 0.0f : pa) + vT_con[0 * 32 + r_s] + lin_carry + 1.0f;
            float tv = fast_tanh(v);
            if (h_s == 0) {
                _Float16 hh = (_Float16)tv;
                _Float16 ll = (_Float16)(tv - (float)hh);
                unsigned int pk = ((unsigned int)h2u(ll) << 16) | (unsigned int)h2u(hh);
                tha[(r_s * 256 + j) ^ ((r_s & 7) << 2)] = pk;
                th_half[0] = tv;
            }
        }
        #pragma unroll
        for (int u = 1; u < 32; ++u) {
            const int j = b * 32 + u;
            const float* wr = wnlm + (size_t)(j - 1) * 256 + b * 32 + h_s * 16;
            float pa = dot16(th_half, wr);
            pa += __shfl_xor(pa, 32, 64);
            float v = pa + vT_con[u * 32 + r_s] + vT_lin[(u - 1) * 32 + r_s] + 1.0f;
            float tv = fast_tanh(v);
            if (h_s == 0) {
                _Float16 hh = (_Float16)tv;
                _Float16 ll = (_Float16)(tv - (float)hh);
                unsigned int pk = ((unsigned int)h2u(ll) << 16) | (unsigned int)h2u(hh);
                tha[(r_s * 256 + j) ^ ((r_s & 7) << 2)] = pk;
            }
            if (h_s == (u >> 4)) th_half[u & 15] = tv;
        }
        lin_carry = vT_lin[31 * 32 + r_s];
    }

    __syncthreads();   // tha complete for stage 3

    // ===== stage 3: out = tanh @ W_out^T + lin_o + 1 =====
    #pragma unroll
    for (int n = 0; n < 4; ++n) {
        f32x4 acc[2];
        acc[0] = (f32x4){0.f, 0.f, 0.f, 0.f};
        acc[1] = (f32x4){0.f, 0.f, 0.f, 0.f};
        // lin_o part (cols 256 + n*16 + ..): 1-product fp16 (proven recipe)
        #pragma unroll
        for (int ks = 0; ks < 16; ++ks) {
            const size_t brow = (size_t)(256 + n * 16 + l15) * 512 + ks * 32 + g * 8;
            f16x8 bh = __builtin_bit_cast(f16x8, *reinterpret_cast<const u16x8*>(wlin_h + brow));
            acc[0] = __builtin_amdgcn_mfma_f32_16x16x32_f16(xfh[0][ks], bh, acc[0], 0, 0, 0);
            acc[1] = __builtin_amdgcn_mfma_f32_16x16x32_f16(xfh[1][ks], bh, acc[1], 0, 0, 0);
        }
        // tanh @ W_out: K=256, fp16-split 3 products
        #pragma unroll
        for (int kc = 0; kc < 8; ++kc) {
            f16x8 ah[2], al[2];
            #pragma unroll
            for (int m = 0; m < 2; ++m)
                tha_frag(tha, m * 16 + l15, kc * 32 + g * 8, &ah[m], &al[m]);
            const size_t wrow = (size_t)(n * 16 + l15) * 256 + kc * 32 + g * 8;
            f16x8 bh = __builtin_bit_cast(f16x8, *reinterpret_cast<const u16x8*>(wout_h + wrow));
            f16x8 bl = __builtin_bit_cast(f16x8, *reinterpret_cast<const u16x8*>(wout_l + wrow));
            #pragma unroll
            for (int m = 0; m < 2; ++m) {
                acc[m] = __builtin_amdgcn_mfma_f32_16x16x32_f16(ah[m], bh, acc[m], 0, 0, 0);
                acc[m] = __builtin_amdgcn_mfma_f32_16x16x32_f16(al[m], bh, acc[m], 0, 0, 0);
                acc[m] = __builtin_amdgcn_mfma_f32_16x16x32_f16(ah[m], bl, acc[m], 0, 0, 0);
            }
        }
        #pragma unroll
        for (int m = 0; m < 2; ++m)
            #pragma unroll
            for (int j = 0; j < 4; ++j)
                out[(row0 + m * 16 + g * 4 + j) * 64 + n * 16 + l15] = acc[m][j] + 1.0f;
    }
}

extern "C" void kernel_launch(void* const* d_in, const int* in_sizes, int n_in,
                              void* d_out, int out_size, void* d_ws, size_t ws_size,
                              hipStream_t stream) {
    (void)in_sizes; (void)n_in; (void)out_size; (void)ws_size;
    const float* x     = (const float*)d_in[0];
    const float* W_lin = (const float*)d_in[1];
    const float* W_nl  = (const float*)d_in[2];
    const float* W_out = (const float*)d_in[3];
    float* out = (float*)d_out;

    char* ws = (char*)d_ws;
    unsigned short* wlin_h = (unsigned short*)(ws);
    unsigned short* wlin_l = (unsigned short*)(ws + 327680);
    float*          wnlm   = (float*)(ws + 655360);
    unsigned short* wnl_h  = (unsigned short*)(ws + 916480);
    unsigned short* wnl_l  = (unsigned short*)(ws + 1047040);
    unsigned short* wout_h = (unsigned short*)(ws + 1177600);
    unsigned short* wout_l = (unsigned short*)(ws + 1210368);

    cascade_prep<<<256, 256, 0, stream>>>(W_lin, W_nl, W_out,
                                          wlin_h, wlin_l, wnlm, wnl_h, wnl_l,
                                          wout_h, wout_l);
    cascade_fused<<<65536 / 32, 64, 0, stream>>>(x, wlin_h, wlin_l, wnlm,
                                                 wnl_h, wnl_l, wout_h, wout_l, out);
}